// Round 14
// baseline (137.921 us; speedup 1.0000x reference)
//
#include <hip/hip_runtime.h>
#include <hip/hip_bf16.h>
#include <math.h>

#define B_   64
#define N_   8192
#define D_   256
#define K_   16
#define NSEG_ 8192
#define NWAVE_ 4096
#define EPS_ 1e-8f
#define NEG_ -3.4e38f

// ws layout (float units)
static const size_t CANDV_OFF = 0;              // 8192 segs * 16 = 131072
static const size_t CANDI_OFF = 131072;         // 131072 ints
static const size_t WORK_OFF  = 262144;         // 8192 ints
static const size_t VTOT_OFF  = 270336;         // 1 int

// ---------------------------------------------------------------------------
// P: build compacted worklist of valid segments. 1 block x 256.
// nseg_b = (it_b>>6)+1 segments contain >=1 valid row; worklist entries are
// (b<<7)|j in b-major order. V = total valid segments (<= 8192).
// ---------------------------------------------------------------------------
__global__ void plan_kernel(const int* __restrict__ iter,
                            int* __restrict__ worklist, int* __restrict__ vtotal) {
    __shared__ int nseg[B_];
    __shared__ int off[B_];
    int tid = threadIdx.x;
    if (tid < B_) nseg[tid] = (min(iter[tid], N_ - 1) >> 6) + 1;
    __syncthreads();
    if (tid == 0) {
        int s = 0;
        for (int b = 0; b < B_; b++) { off[b] = s; s += nseg[b]; }
        *vtotal = s;
    }
    __syncthreads();
    for (int b = 0; b < B_; b++) {
        int n = nseg[b], o = off[b];
        for (int j = tid; j < n; j += 256) worklist[o + j] = (b << 7) | j;
    }
}

// ---------------------------------------------------------------------------
// A: sims + per-wave top-16 via bitonic sort, over the COMPACTED worklist.
// 1024 blocks x 256 = 4096 waves (16/CU); wave i handles worklist[i + 4096k]
// -> per-CU work balanced to +-1 segment (fixes the j = c mod 32 aliasing
// that concentrated ~2 MB on position-0 CUs). Inner loop verbatim R3.
// Fill phase writes (0, lowest-idx) candidates for fully-masked segments.
// ---------------------------------------------------------------------------
__global__ void __launch_bounds__(256)
simtopk_kernel(const float* __restrict__ q, const float* __restrict__ km,
               const int* __restrict__ iter,
               const int* __restrict__ worklist, const int* __restrict__ vtotal,
               float* __restrict__ cand_v, int* __restrict__ cand_i) {
    int tid  = threadIdx.x;
    int w    = tid >> 6, lane = tid & 63;
    int g    = lane >> 4, p = lane & 15;
    int wave_id = (blockIdx.x << 2) + w;
    int V = *vtotal;                            // uniform broadcast load

    for (int v = wave_id; v < V; v += NWAVE_) {
        int seg = worklist[v];                  // uniform per wave
        int b   = seg >> 7;
        int r0  = (seg & 127) << 6;
        int it  = iter[b];
        size_t cbase = (size_t)seg * K_;

        float4 q4[4];
        #pragma unroll
        for (int kk = 0; kk < 4; kk++)
            q4[kk] = *(const float4*)(q + (size_t)b * D_ + kk * 64 + p * 4);
        float qq = 0.f;
        #pragma unroll
        for (int kk = 0; kk < 4; kk++)
            qq += q4[kk].x*q4[kk].x + q4[kk].y*q4[kk].y + q4[kk].z*q4[kk].z + q4[kk].w*q4[kk].w;
        #pragma unroll
        for (int off = 8; off; off >>= 1) qq += __shfl_xor(qq, off);
        float qn = sqrtf(qq);

        float keepv = 0.f;
        const float* kmb = km + (size_t)b * N_ * D_;
        for (int t = 0; t < 8; t++) {
            int ra = r0 + (t << 3) + (g << 1);
            int rb = ra + 1;
            const float* pa = kmb + (size_t)min(ra, it) * D_;   // clamp: branch-free
            const float* pb = kmb + (size_t)min(rb, it) * D_;
            float4 ka0 = *(const float4*)(pa +   0 + p * 4);
            float4 ka1 = *(const float4*)(pa +  64 + p * 4);
            float4 ka2 = *(const float4*)(pa + 128 + p * 4);
            float4 ka3 = *(const float4*)(pa + 192 + p * 4);
            float4 kb0 = *(const float4*)(pb +   0 + p * 4);
            float4 kb1 = *(const float4*)(pb +  64 + p * 4);
            float4 kb2 = *(const float4*)(pb + 128 + p * 4);
            float4 kb3 = *(const float4*)(pb + 192 + p * 4);
            float dota = ka0.x*q4[0].x + ka0.y*q4[0].y + ka0.z*q4[0].z + ka0.w*q4[0].w
                       + ka1.x*q4[1].x + ka1.y*q4[1].y + ka1.z*q4[1].z + ka1.w*q4[1].w
                       + ka2.x*q4[2].x + ka2.y*q4[2].y + ka2.z*q4[2].z + ka2.w*q4[2].w
                       + ka3.x*q4[3].x + ka3.y*q4[3].y + ka3.z*q4[3].z + ka3.w*q4[3].w;
            float sqa  = ka0.x*ka0.x + ka0.y*ka0.y + ka0.z*ka0.z + ka0.w*ka0.w
                       + ka1.x*ka1.x + ka1.y*ka1.y + ka1.z*ka1.z + ka1.w*ka1.w
                       + ka2.x*ka2.x + ka2.y*ka2.y + ka2.z*ka2.z + ka2.w*ka2.w
                       + ka3.x*ka3.x + ka3.y*ka3.y + ka3.z*ka3.z + ka3.w*ka3.w;
            float dotb = kb0.x*q4[0].x + kb0.y*q4[0].y + kb0.z*q4[0].z + kb0.w*q4[0].w
                       + kb1.x*q4[1].x + kb1.y*q4[1].y + kb1.z*q4[1].z + kb1.w*q4[1].w
                       + kb2.x*q4[2].x + kb2.y*q4[2].y + kb2.z*q4[2].z + kb2.w*q4[2].w
                       + kb3.x*q4[3].x + kb3.y*q4[3].y + kb3.z*q4[3].z + kb3.w*q4[3].w;
            float sqb  = kb0.x*kb0.x + kb0.y*kb0.y + kb0.z*kb0.z + kb0.w*kb0.w
                       + kb1.x*kb1.x + kb1.y*kb1.y + kb1.z*kb1.z + kb1.w*kb1.w
                       + kb2.x*kb2.x + kb2.y*kb2.y + kb2.z*kb2.z + kb2.w*kb2.w
                       + kb3.x*kb3.x + kb3.y*kb3.y + kb3.z*kb3.z + kb3.w*kb3.w;
            #pragma unroll
            for (int off = 8; off; off >>= 1) {     // 4 independent chains
                dota += __shfl_xor(dota, off);
                sqa  += __shfl_xor(sqa,  off);
                dotb += __shfl_xor(dotb, off);
                sqb  += __shfl_xor(sqb,  off);
            }
            float sa = (ra <= it) ? dota / fmaxf(sqrtf(sqa) * qn, EPS_) : 0.f;
            float sb = (rb <= it) ? dotb / fmaxf(sqrtf(sqb) * qn, EPS_) : 0.f;
            keepv = (p == 2 * t)     ? sa : keepv;  // VALU keep-assign, no LDS
            keepv = (p == 2 * t + 1) ? sb : keepv;
        }
        int keepi = r0 + ((p >> 1) << 3) + (g << 1) + (p & 1);

        // wave64 bitonic sort: (value desc, index asc); lanes 0..15 = top-16
        #pragma unroll
        for (int k = 2; k <= 64; k <<= 1) {
            #pragma unroll
            for (int j2 = k >> 1; j2 > 0; j2 >>= 1) {
                float pv = __shfl_xor(keepv, j2);
                int   pi = __shfl_xor(keepi, j2);
                bool up         = ((lane & k) == 0);
                bool is_lower   = ((lane & j2) == 0);
                bool mine_first = (keepv > pv) || (keepv == pv && keepi < pi);
                bool take_mine  = ((is_lower == up) == mine_first);
                if (!take_mine) { keepv = pv; keepi = pi; }
            }
        }
        if (lane < K_) { cand_v[cbase + lane] = keepv; cand_i[cbase + lane] = keepi; }
    }

    // fill phase: fully-masked segments emit zeros at their 16 lowest indices
    for (int s = wave_id; s < NSEG_; s += NWAVE_) {
        int b  = s >> 7;
        int r0 = (s & 127) << 6;
        if (r0 > iter[b] && lane < K_) {
            cand_v[(size_t)s * K_ + lane] = 0.f;
            cand_i[(size_t)s * K_ + lane] = r0 + lane;
        }
    }
}

// ---------------------------------------------------------------------------
// B: fused tail (verbatim R13). 64 blocks x 768.
// ---------------------------------------------------------------------------
__global__ void __launch_bounds__(768)
tail_kernel(const float* __restrict__ cand_v, const int* __restrict__ cand_i,
            const float* __restrict__ vm, const int* __restrict__ iter,
            const float* __restrict__ inw, const float* __restrict__ inb,
            const float* __restrict__ ow, const float* __restrict__ ob,
            float* __restrict__ out) {
    int b = blockIdx.x;
    int tid = threadIdx.x, lane = tid & 63;
    int it = iter[b];
    if (it == 0) {                              // block-uniform early out
        if (tid < D_) out[(size_t)b * D_ + tid] = 0.f;
        return;
    }

    __shared__ int   seli[K_];
    __shared__ float scl[K_];
    __shared__ float xs[D_][K_];                // scaled x^T: [d][k]
    __shared__ float qs[K_][260];
    __shared__ float ks[K_][260];
    __shared__ float vs[K_][260];
    __shared__ float attnS[K_][K_];
    __shared__ float colsum[K_];
    __shared__ float so[D_];

    if (tid < 64) {                             // single-wave merge, no barriers
        float cv[32]; int ci[32];
        #pragma unroll
        for (int j = 0; j < 32; j++) {
            cv[j] = cand_v[(size_t)b * 2048 + (j << 6) + lane];
            ci[j] = cand_i[(size_t)b * 2048 + (j << 6) + lane];
        }
        float selv[K_]; int selidx[K_];
        for (int sel = 0; sel < K_; sel++) {
            float bv = cv[0]; int bi = ci[0];
            #pragma unroll
            for (int j = 1; j < 32; j++)
                if (cv[j] > bv || (cv[j] == bv && ci[j] < bi)) { bv = cv[j]; bi = ci[j]; }
            #pragma unroll
            for (int off = 32; off; off >>= 1) {
                float ov = __shfl_xor(bv, off);
                int   oi = __shfl_xor(bi, off);
                if (ov > bv || (ov == bv && oi < bi)) { bv = ov; bi = oi; }
            }
            #pragma unroll
            for (int j = 0; j < 32; j++)        // indices globally unique
                if (ci[j] == bi) cv[j] = NEG_;
            selv[sel] = bv; selidx[sel] = bi;
            if (lane == 0) seli[sel] = bi;
        }
        float m = NEG_;
        #pragma unroll
        for (int jj = 0; jj < K_; jj++) m = fmaxf(m, selv[jj]);
        float ssum = 0.f;
        #pragma unroll
        for (int jj = 0; jj < K_; jj++) ssum += expf(selv[jj] - m);
        if (lane < K_) {
            float wgt = expf(selv[lane] - m) / ssum;
            scl[lane] = (selidx[lane] <= it) ? wgt : 0.f;   // masked pick -> 0
        }
    }
    __syncthreads();

    if (tid < D_) {                             // gather scaled x^T
        #pragma unroll
        for (int kk = 0; kk < K_; kk += 4) {
            float4 px;
            px.x = scl[kk+0] * vm[((size_t)b * N_ + seli[kk+0]) * D_ + tid];
            px.y = scl[kk+1] * vm[((size_t)b * N_ + seli[kk+1]) * D_ + tid];
            px.z = scl[kk+2] * vm[((size_t)b * N_ + seli[kk+2]) * D_ + tid];
            px.w = scl[kk+3] * vm[((size_t)b * N_ + seli[kk+3]) * D_ + tid];
            *(float4*)(&xs[tid][kk]) = px;
        }
    }
    __syncthreads();

    {   // all 768 threads: which = tid>>8, e = tid&255
        int which = tid >> 8, e = tid & 255;
        float acc[K_];
        #pragma unroll
        for (int k = 0; k < K_; k++) acc[k] = 0.f;
        const float* wrow = inw + (size_t)(which * D_ + e) * D_;
        for (int d = 0; d < D_; d += 4) {
            float4 wv4 = *(const float4*)(wrow + d);
            float wk[4] = {wv4.x, wv4.y, wv4.z, wv4.w};
            #pragma unroll
            for (int dd = 0; dd < 4; dd++) {
                float wgt = wk[dd];
                float4 x0 = *(const float4*)(&xs[d + dd][0]);    // broadcast
                float4 x1 = *(const float4*)(&xs[d + dd][4]);
                float4 x2 = *(const float4*)(&xs[d + dd][8]);
                float4 x3 = *(const float4*)(&xs[d + dd][12]);
                acc[0]  += x0.x * wgt; acc[1]  += x0.y * wgt; acc[2]  += x0.z * wgt; acc[3]  += x0.w * wgt;
                acc[4]  += x1.x * wgt; acc[5]  += x1.y * wgt; acc[6]  += x1.z * wgt; acc[7]  += x1.w * wgt;
                acc[8]  += x2.x * wgt; acc[9]  += x2.y * wgt; acc[10] += x2.z * wgt; acc[11] += x2.w * wgt;
                acc[12] += x3.x * wgt; acc[13] += x3.y * wgt; acc[14] += x3.z * wgt; acc[15] += x3.w * wgt;
            }
        }
        float bias = inb[which * D_ + e];
        float* dst = (which == 0) ? &qs[0][0] : (which == 1) ? &ks[0][0] : &vs[0][0];
        #pragma unroll
        for (int k = 0; k < K_; k++)
            dst[k * 260 + e] = acc[k] + bias;   // lanes -> consecutive e: no conflict
    }
    __syncthreads();

    if (tid < D_) {                             // attention scores 16x16
        int i = tid >> 4, j = tid & 15;
        float s = 0.f;
        for (int d4 = 0; d4 < 64; d4++) {
            float4 qv = *(const float4*)(&qs[i][d4 * 4]);
            float4 kv = *(const float4*)(&ks[j][d4 * 4]);
            s += qv.x*kv.x + qv.y*kv.y + qv.z*kv.z + qv.w*kv.w;
        }
        attnS[i][j] = s * 0.0625f;              // 1/sqrt(256)
    }
    __syncthreads();
    if (tid < K_) {                             // softmax row tid
        float m = NEG_;
        for (int jj = 0; jj < K_; jj++) m = fmaxf(m, attnS[tid][jj]);
        float ssum = 0.f;
        for (int jj = 0; jj < K_; jj++) ssum += expf(attnS[tid][jj] - m);
        float inv = 1.f / ssum;
        for (int jj = 0; jj < K_; jj++) attnS[tid][jj] = expf(attnS[tid][jj] - m) * inv;
    }
    __syncthreads();
    if (tid < K_) {                             // token-sum commutes: colsum
        float c = 0.f;
        for (int ii = 0; ii < K_; ii++) c += attnS[ii][tid];
        colsum[tid] = c;
    }
    __syncthreads();
    if (tid < D_) {
        float acc = 0.f;
        #pragma unroll
        for (int jj = 0; jj < K_; jj++) acc += colsum[jj] * vs[jj][tid];
        so[tid] = acc;
    }
    __syncthreads();
    if (tid < D_) {
        float o = 0.f;
        const float* orow = ow + (size_t)tid * D_;
        for (int e = 0; e < D_; e += 4) {
            float4 wv = *(const float4*)(orow + e);
            float4 sv = *(const float4*)(&so[e]);
            o += sv.x*wv.x + sv.y*wv.y + sv.z*wv.z + sv.w*wv.w;
        }
        out[(size_t)b * D_ + tid] = o + 16.f * ob[tid];
    }
}

extern "C" void kernel_launch(void* const* d_in, const int* in_sizes, int n_in,
                              void* d_out, int out_size, void* d_ws, size_t ws_size,
                              hipStream_t stream) {
    const float* q   = (const float*)d_in[0];
    const float* km  = (const float*)d_in[1];
    const float* vm  = (const float*)d_in[2];
    const int*   it  = (const int*)  d_in[3];
    const float* inw = (const float*)d_in[4];
    const float* inb = (const float*)d_in[5];
    const float* ow  = (const float*)d_in[6];
    const float* ob  = (const float*)d_in[7];
    float* out = (float*)d_out;

    float* ws       = (float*)d_ws;
    float* cand_v   = ws + CANDV_OFF;
    int*   cand_i   = (int*)(ws + CANDI_OFF);
    int*   worklist = (int*)(ws + WORK_OFF);
    int*   vtotal   = (int*)(ws + VTOT_OFF);

    plan_kernel<<<dim3(1), dim3(256), 0, stream>>>(it, worklist, vtotal);
    simtopk_kernel<<<dim3(1024), dim3(256), 0, stream>>>(q, km, it, worklist, vtotal, cand_v, cand_i);
    tail_kernel<<<dim3(B_), dim3(768), 0, stream>>>(cand_v, cand_i, vm, it, inw, inb, ow, ob, out);
}

// Round 16
// 131.623 us; speedup vs baseline: 1.0478x; 1.0478x over previous
//
#include <hip/hip_runtime.h>
#include <hip/hip_bf16.h>
#include <math.h>

#define B_   64
#define N_   8192
#define D_   256
#define K_   16
#define EPS_ 1e-8f
#define NEG_ -3.4e38f

// ws layout (float units)
static const size_t CANDV_OFF = 0;              // 8192 segs * 16 = 131072
static const size_t CANDI_OFF = 131072;         // 131072 ints

typedef float floatx4 __attribute__((ext_vector_type(4)));

__device__ __forceinline__ float4 ldnt4(const float* p) {
    floatx4 v = __builtin_nontemporal_load((const floatx4*)p);
    return make_float4(v.x, v.y, v.z, v.w);
}

// ---------------------------------------------------------------------------
// A: sims + per-wave top-16 via bitonic sort (R3/R13 structure — best
// measured). Single change vs R13: km loads are NON-TEMPORAL (nt) — km is
// a 512MB stream with zero reuse; nt relieves L1 line allocation on the
// read path (MSHR-limit theory for the ~2.5 TB/s read plateau).
// 2048 blocks x 256; wave-segment = 64 rows.
// ---------------------------------------------------------------------------
__global__ void __launch_bounds__(256)
simtopk_kernel(const float* __restrict__ q, const float* __restrict__ km,
               const int* __restrict__ iter,
               float* __restrict__ cand_v, int* __restrict__ cand_i) {
    int tid  = threadIdx.x;
    int w    = tid >> 6, lane = tid & 63;
    int g    = lane >> 4, p = lane & 15;
    int item = (blockIdx.x << 2) + w;           // [0, 8192)
    int b    = item >> 7;
    int r0   = (item & 127) << 6;
    int it   = iter[b];
    size_t cbase = (size_t)item * K_;

    if (r0 > it) {   // fully masked: zeros at the 16 lowest indices
        if (lane < K_) { cand_v[cbase + lane] = 0.f; cand_i[cbase + lane] = r0 + lane; }
        return;
    }

    float4 q4[4];
    #pragma unroll
    for (int kk = 0; kk < 4; kk++)
        q4[kk] = *(const float4*)(q + (size_t)b * D_ + kk * 64 + p * 4);
    float qq = 0.f;
    #pragma unroll
    for (int kk = 0; kk < 4; kk++)
        qq += q4[kk].x*q4[kk].x + q4[kk].y*q4[kk].y + q4[kk].z*q4[kk].z + q4[kk].w*q4[kk].w;
    #pragma unroll
    for (int off = 8; off; off >>= 1) qq += __shfl_xor(qq, off);
    float qn = sqrtf(qq);

    float keepv = 0.f;
    const float* kmb = km + (size_t)b * N_ * D_;
    for (int t = 0; t < 8; t++) {
        int ra = r0 + (t << 3) + (g << 1);
        int rb = ra + 1;
        const float* pa = kmb + (size_t)min(ra, it) * D_;   // clamp: branch-free
        const float* pb = kmb + (size_t)min(rb, it) * D_;
        float4 ka0 = ldnt4(pa +   0 + p * 4);
        float4 ka1 = ldnt4(pa +  64 + p * 4);
        float4 ka2 = ldnt4(pa + 128 + p * 4);
        float4 ka3 = ldnt4(pa + 192 + p * 4);
        float4 kb0 = ldnt4(pb +   0 + p * 4);
        float4 kb1 = ldnt4(pb +  64 + p * 4);
        float4 kb2 = ldnt4(pb + 128 + p * 4);
        float4 kb3 = ldnt4(pb + 192 + p * 4);
        float dota = ka0.x*q4[0].x + ka0.y*q4[0].y + ka0.z*q4[0].z + ka0.w*q4[0].w
                   + ka1.x*q4[1].x + ka1.y*q4[1].y + ka1.z*q4[1].z + ka1.w*q4[1].w
                   + ka2.x*q4[2].x + ka2.y*q4[2].y + ka2.z*q4[2].z + ka2.w*q4[2].w
                   + ka3.x*q4[3].x + ka3.y*q4[3].y + ka3.z*q4[3].z + ka3.w*q4[3].w;
        float sqa  = ka0.x*ka0.x + ka0.y*ka0.y + ka0.z*ka0.z + ka0.w*ka0.w
                   + ka1.x*ka1.x + ka1.y*ka1.y + ka1.z*ka1.z + ka1.w*ka1.w
                   + ka2.x*ka2.x + ka2.y*ka2.y + ka2.z*ka2.z + ka2.w*ka2.w
                   + ka3.x*ka3.x + ka3.y*ka3.y + ka3.z*ka3.z + ka3.w*ka3.w;
        float dotb = kb0.x*q4[0].x + kb0.y*q4[0].y + kb0.z*q4[0].z + kb0.w*q4[0].w
                   + kb1.x*q4[1].x + kb1.y*q4[1].y + kb1.z*q4[1].z + kb1.w*q4[1].w
                   + kb2.x*q4[2].x + kb2.y*q4[2].y + kb2.z*q4[2].z + kb2.w*q4[2].w
                   + kb3.x*q4[3].x + kb3.y*q4[3].y + kb3.z*q4[3].z + kb3.w*q4[3].w;
        float sqb  = kb0.x*kb0.x + kb0.y*kb0.y + kb0.z*kb0.z + kb0.w*kb0.w
                   + kb1.x*kb1.x + kb1.y*kb1.y + kb1.z*kb1.z + kb1.w*kb1.w
                   + kb2.x*kb2.x + kb2.y*kb2.y + kb2.z*kb2.z + kb2.w*kb2.w
                   + kb3.x*kb3.x + kb3.y*kb3.y + kb3.z*kb3.z + kb3.w*kb3.w;
        #pragma unroll
        for (int off = 8; off; off >>= 1) {     // 4 independent chains, 16-lane
            dota += __shfl_xor(dota, off);
            sqa  += __shfl_xor(sqa,  off);
            dotb += __shfl_xor(dotb, off);
            sqb  += __shfl_xor(sqb,  off);
        }
        float sa = (ra <= it) ? dota / fmaxf(sqrtf(sqa) * qn, EPS_) : 0.f;
        float sb = (rb <= it) ? dotb / fmaxf(sqrtf(sqb) * qn, EPS_) : 0.f;
        keepv = (p == 2 * t)     ? sa : keepv;  // VALU keep-assign, no LDS
        keepv = (p == 2 * t + 1) ? sb : keepv;
    }
    int keepi = r0 + ((p >> 1) << 3) + (g << 1) + (p & 1);

    // wave64 bitonic sort: order = (value desc, index asc); lane0 = best
    #pragma unroll
    for (int k = 2; k <= 64; k <<= 1) {
        #pragma unroll
        for (int j = k >> 1; j > 0; j >>= 1) {
            float pv = __shfl_xor(keepv, j);
            int   pi = __shfl_xor(keepi, j);
            bool up         = ((lane & k) == 0);
            bool is_lower   = ((lane & j) == 0);
            bool mine_first = (keepv > pv) || (keepv == pv && keepi < pi);
            bool take_mine  = ((is_lower == up) == mine_first);
            if (!take_mine) { keepv = pv; keepi = pi; }
        }
    }
    if (lane < K_) { cand_v[cbase + lane] = keepv; cand_i[cbase + lane] = keepi; }
}

// ---------------------------------------------------------------------------
// B: fused tail (verbatim R13). 64 blocks x 768.
// ---------------------------------------------------------------------------
__global__ void __launch_bounds__(768)
tail_kernel(const float* __restrict__ cand_v, const int* __restrict__ cand_i,
            const float* __restrict__ vm, const int* __restrict__ iter,
            const float* __restrict__ inw, const float* __restrict__ inb,
            const float* __restrict__ ow, const float* __restrict__ ob,
            float* __restrict__ out) {
    int b = blockIdx.x;
    int tid = threadIdx.x, lane = tid & 63;
    int it = iter[b];
    if (it == 0) {                              // block-uniform early out
        if (tid < D_) out[(size_t)b * D_ + tid] = 0.f;
        return;
    }

    __shared__ int   seli[K_];
    __shared__ float scl[K_];
    __shared__ float xs[D_][K_];                // scaled x^T: [d][k]
    __shared__ float qs[K_][260];
    __shared__ float ks[K_][260];
    __shared__ float vs[K_][260];
    __shared__ float attnS[K_][K_];
    __shared__ float colsum[K_];
    __shared__ float so[D_];

    if (tid < 64) {                             // single-wave merge, no barriers
        float cv[32]; int ci[32];
        #pragma unroll
        for (int j = 0; j < 32; j++) {
            cv[j] = cand_v[(size_t)b * 2048 + (j << 6) + lane];
            ci[j] = cand_i[(size_t)b * 2048 + (j << 6) + lane];
        }
        float selv[K_]; int selidx[K_];
        for (int sel = 0; sel < K_; sel++) {
            float bv = cv[0]; int bi = ci[0];
            #pragma unroll
            for (int j = 1; j < 32; j++)
                if (cv[j] > bv || (cv[j] == bv && ci[j] < bi)) { bv = cv[j]; bi = ci[j]; }
            #pragma unroll
            for (int off = 32; off; off >>= 1) {
                float ov = __shfl_xor(bv, off);
                int   oi = __shfl_xor(bi, off);
                if (ov > bv || (ov == bv && oi < bi)) { bv = ov; bi = oi; }
            }
            #pragma unroll
            for (int j = 0; j < 32; j++)        // indices globally unique
                if (ci[j] == bi) cv[j] = NEG_;
            selv[sel] = bv; selidx[sel] = bi;
            if (lane == 0) seli[sel] = bi;
        }
        float m = NEG_;
        #pragma unroll
        for (int jj = 0; jj < K_; jj++) m = fmaxf(m, selv[jj]);
        float ssum = 0.f;
        #pragma unroll
        for (int jj = 0; jj < K_; jj++) ssum += expf(selv[jj] - m);
        if (lane < K_) {
            float wgt = expf(selv[lane] - m) / ssum;
            scl[lane] = (selidx[lane] <= it) ? wgt : 0.f;   // masked pick -> 0
        }
    }
    __syncthreads();

    if (tid < D_) {                             // gather scaled x^T
        #pragma unroll
        for (int kk = 0; kk < K_; kk += 4) {
            float4 px;
            px.x = scl[kk+0] * vm[((size_t)b * N_ + seli[kk+0]) * D_ + tid];
            px.y = scl[kk+1] * vm[((size_t)b * N_ + seli[kk+1]) * D_ + tid];
            px.z = scl[kk+2] * vm[((size_t)b * N_ + seli[kk+2]) * D_ + tid];
            px.w = scl[kk+3] * vm[((size_t)b * N_ + seli[kk+3]) * D_ + tid];
            *(float4*)(&xs[tid][kk]) = px;
        }
    }
    __syncthreads();

    {   // all 768 threads: which = tid>>8, e = tid&255
        int which = tid >> 8, e = tid & 255;
        float acc[K_];
        #pragma unroll
        for (int k = 0; k < K_; k++) acc[k] = 0.f;
        const float* wrow = inw + (size_t)(which * D_ + e) * D_;
        for (int d = 0; d < D_; d += 4) {
            float4 wv4 = *(const float4*)(wrow + d);
            float wk[4] = {wv4.x, wv4.y, wv4.z, wv4.w};
            #pragma unroll
            for (int dd = 0; dd < 4; dd++) {
                float wgt = wk[dd];
                float4 x0 = *(const float4*)(&xs[d + dd][0]);    // broadcast
                float4 x1 = *(const float4*)(&xs[d + dd][4]);
                float4 x2 = *(const float4*)(&xs[d + dd][8]);
                float4 x3 = *(const float4*)(&xs[d + dd][12]);
                acc[0]  += x0.x * wgt; acc[1]  += x0.y * wgt; acc[2]  += x0.z * wgt; acc[3]  += x0.w * wgt;
                acc[4]  += x1.x * wgt; acc[5]  += x1.y * wgt; acc[6]  += x1.z * wgt; acc[7]  += x1.w * wgt;
                acc[8]  += x2.x * wgt; acc[9]  += x2.y * wgt; acc[10] += x2.z * wgt; acc[11] += x2.w * wgt;
                acc[12] += x3.x * wgt; acc[13] += x3.y * wgt; acc[14] += x3.z * wgt; acc[15] += x3.w * wgt;
            }
        }
        float bias = inb[which * D_ + e];
        float* dst = (which == 0) ? &qs[0][0] : (which == 1) ? &ks[0][0] : &vs[0][0];
        #pragma unroll
        for (int k = 0; k < K_; k++)
            dst[k * 260 + e] = acc[k] + bias;   // lanes -> consecutive e: no conflict
    }
    __syncthreads();

    if (tid < D_) {                             // attention scores 16x16
        int i = tid >> 4, j = tid & 15;
        float s = 0.f;
        for (int d4 = 0; d4 < 64; d4++) {
            float4 qv = *(const float4*)(&qs[i][d4 * 4]);
            float4 kv = *(const float4*)(&ks[j][d4 * 4]);
            s += qv.x*kv.x + qv.y*kv.y + qv.z*kv.z + qv.w*kv.w;
        }
        attnS[i][j] = s * 0.0625f;              // 1/sqrt(256)
    }
    __syncthreads();
    if (tid < K_) {                             // softmax row tid
        float m = NEG_;
        for (int jj = 0; jj < K_; jj++) m = fmaxf(m, attnS[tid][jj]);
        float ssum = 0.f;
        for (int jj = 0; jj < K_; jj++) ssum += expf(attnS[tid][jj] - m);
        float inv = 1.f / ssum;
        for (int jj = 0; jj < K_; jj++) attnS[tid][jj] = expf(attnS[tid][jj] - m) * inv;
    }
    __syncthreads();
    if (tid < K_) {                             // token-sum commutes: colsum
        float c = 0.f;
        for (int ii = 0; ii < K_; ii++) c += attnS[ii][tid];
        colsum[tid] = c;
    }
    __syncthreads();
    if (tid < D_) {
        float acc = 0.f;
        #pragma unroll
        for (int jj = 0; jj < K_; jj++) acc += colsum[jj] * vs[jj][tid];
        so[tid] = acc;
    }
    __syncthreads();
    if (tid < D_) {
        float o = 0.f;
        const float* orow = ow + (size_t)tid * D_;
        for (int e = 0; e < D_; e += 4) {
            float4 wv = *(const float4*)(orow + e);
            float4 sv = *(const float4*)(&so[e]);
            o += sv.x*wv.x + sv.y*wv.y + sv.z*wv.z + sv.w*wv.w;
        }
        out[(size_t)b * D_ + tid] = o + 16.f * ob[tid];
    }
}

extern "C" void kernel_launch(void* const* d_in, const int* in_sizes, int n_in,
                              void* d_out, int out_size, void* d_ws, size_t ws_size,
                              hipStream_t stream) {
    const float* q   = (const float*)d_in[0];
    const float* km  = (const float*)d_in[1];
    const float* vm  = (const float*)d_in[2];
    const int*   it  = (const int*)  d_in[3];
    const float* inw = (const float*)d_in[4];
    const float* inb = (const float*)d_in[5];
    const float* ow  = (const float*)d_in[6];
    const float* ob  = (const float*)d_in[7];
    float* out = (float*)d_out;

    float* ws     = (float*)d_ws;
    float* cand_v = ws + CANDV_OFF;
    int*   cand_i = (int*)(ws + CANDI_OFF);

    simtopk_kernel<<<dim3(2048), dim3(256), 0, stream>>>(q, km, it, cand_v, cand_i);
    tail_kernel<<<dim3(B_), dim3(768), 0, stream>>>(cand_v, cand_i, vm, it, inw, inb, ow, ob, out);
}